// Round 1
// 945.347 us; speedup vs baseline: 1.2138x; 1.2138x over previous
//
#include <hip/hip_runtime.h>
#include <hip/hip_bf16.h>

#define BDIM 4
#define VDIM 20000
#define DDIM 64
#define RDIM 64
#define EDIM 200000
#define BV (BDIM*VDIM)
#define LN_EPS 1e-5f
#define NBB 250           // qkproj blocks per batch

typedef __hip_bfloat16 bf16;

__device__ __forceinline__ float ldf(const float* p, size_t i){ return p[i]; }
__device__ __forceinline__ float ldf(const bf16* p, size_t i){ return __bfloat162float(p[i]); }
__device__ __forceinline__ void stf(float* p, size_t i, float v){ p[i] = v; }
__device__ __forceinline__ void stf(bf16* p, size_t i, float v){ p[i] = __float2bfloat16(v); }

__device__ __forceinline__ float wave_sum64(float x){
  #pragma unroll
  for (int o = 32; o > 0; o >>= 1) x += __shfl_xor(x, o, 64);
  return x;
}
__device__ __forceinline__ float head_sum16(float x){
  #pragma unroll
  for (int o = 8; o > 0; o >>= 1) x += __shfl_xor(x, o, 64);
  return x;
}
__device__ __forceinline__ float dot4(float4 a, float4 b){
  return a.x*b.x + a.y*b.y + a.z*b.z + a.w*b.w;
}

// Wave-private LDS ordering: hardware DS ops from one wave execute in order,
// so write->read of a wave-private LDS region needs NO s_barrier. We only
// need to stop the compiler from reordering across the point.
__device__ __forceinline__ void wsync(){
  __builtin_amdgcn_wave_barrier();
  __asm__ volatile("" ::: "memory");
}

// ---- diagnostic fill ----
__global__ void fill_kernel(float* __restrict__ out, float v, int n){
  int t = blockIdx.x * 256 + threadIdx.x;
  if (t < n) out[t] = v;
}

// ---- detect 64-bit index layout once (was: per-block serial scan) ----
__global__ void detect_kernel(const int* __restrict__ ei_raw, int* __restrict__ flag){
  int tid = threadIdx.x;
  int nz = 0;
  for (int j = 2*tid + 1; j < 1024; j += 512) nz |= (ei_raw[j] != 0);
  nz = __any(nz);
  __shared__ int r[4];
  if ((tid & 63) == 0) r[tid >> 6] = nz;
  __syncthreads();
  if (tid == 0) flag[0] = (r[0] | r[1] | r[2] | r[3]) ? 0 : 1;   // 1 => 64-bit
}

__global__ void prep_idx_kernel(const int* __restrict__ ei_raw, const int* __restrict__ hi_raw,
                                const int* __restrict__ flag,
                                int* __restrict__ ei, int* __restrict__ hi){
  int is64 = flag[0];
  int t = blockIdx.x * 256 + threadIdx.x;
  if (t < 3*EDIM) ei[t] = is64 ? ei_raw[2*t] : ei_raw[t];
  if (t < BDIM)   hi[t] = is64 ? hi_raw[2*t] : hi_raw[t];
}

__global__ void zero_kernel(int* __restrict__ counts){
  int i = blockIdx.x * 256 + threadIdx.x;
  if (i < VDIM + 1) counts[i] = 0;
}

__global__ void count_kernel(const int* __restrict__ ei, int* __restrict__ counts){
  int e = blockIdx.x * 256 + threadIdx.x;
  if (e < EDIM){
    int dst = ei[e*3], rel = ei[e*3+1], src = ei[e*3+2];
    if ((unsigned)dst < VDIM && (unsigned)rel < RDIM && (unsigned)src < VDIM)
      atomicAdd(&counts[dst], 1);
  }
}

// ---- scan: per-thread segments + one wave scan, 1 barrier total ----
__global__ void scan_kernel(const int* __restrict__ counts, int* __restrict__ row_ptr, int* __restrict__ cursor){
  __shared__ int wsum[4];
  int tid = threadIdx.x, lane = tid & 63, wid = tid >> 6;
  const int SEG = (VDIM + 255) / 256;        // 79
  int lo = tid * SEG;
  int hi = lo + SEG; if (hi > VDIM) hi = VDIM;
  int s = 0;
  for (int i = lo; i < hi; i++) s += counts[i];
  int x = s;
  #pragma unroll
  for (int o = 1; o < 64; o <<= 1){
    int t = __shfl_up(x, o, 64);
    if (lane >= o) x += t;
  }
  if (lane == 63) wsum[wid] = x;
  __syncthreads();
  int wo = 0;
  for (int w = 0; w < wid; w++) wo += wsum[w];
  int run = wo + x - s;                      // exclusive prefix of this thread's segment
  for (int i = lo; i < hi; i++){
    row_ptr[i] = run; cursor[i] = run; run += counts[i];
  }
  if (tid == 255) row_ptr[VDIM] = run;       // total
}

__global__ void scatter_kernel(const int* __restrict__ ei, int* __restrict__ cursor,
                               int2* __restrict__ pk){
  int e = blockIdx.x * 256 + threadIdx.x;
  if (e < EDIM){
    int dst = ei[e*3], rel = ei[e*3+1], src = ei[e*3+2];
    if ((unsigned)dst < VDIM && (unsigned)rel < RDIM && (unsigned)src < VDIM){
      int p = atomicAdd(&cursor[dst], 1);
      pk[p] = make_int2(rel, src);
    }
  }
}

// ---- z projections (float4 weight reads) ----
__global__ void zcalc_kernel(const float* __restrict__ z,
                             const float* __restrict__ qkzw, const float* __restrict__ qkzb,
                             const float* __restrict__ vfw,  const float* __restrict__ vfb,
                             float* __restrict__ qk_z, float* __restrict__ zr){
  int idx = blockIdx.x * 256 + threadIdx.x;
  if (idx >= 49152) return;
  int which = idx >> 14;
  int r = idx & 16383;
  int b = r >> 12;
  int j = r & 4095;
  const float* wrow; float bias; float* outp;
  if (which == 0){ wrow = qkzw + (size_t)j*DDIM; bias = qkzb[j]; outp = qk_z; }
  else { int i = which - 1; wrow = vfw + (size_t)(i*4096 + j)*DDIM; bias = vfb[i*4096 + j]; outp = zr + i*16384; }
  const float4* zr4 = (const float4*)(z + (size_t)b*DDIM);
  const float4* wr4 = (const float4*)wrow;
  float acc = bias;
  #pragma unroll
  for (int i = 0; i < 16; i++) acc += dot4(zr4[i], wr4[i]);
  outp[r] = acc;
}

// ---- rspmm gather (CSR, packed idx), 2 edges in flight ----
template<typename T>
__global__ __launch_bounds__(256) void rspmm_gather(
    const int* __restrict__ row_ptr, const int2* __restrict__ pk,
    const float* __restrict__ zrel, const T* __restrict__ X, T* __restrict__ out){
  int v = blockIdx.x;
  int b = threadIdx.x >> 6, d = threadIdx.x & 63;
  int s = row_ptr[v], e = row_ptr[v+1];
  const float* zb = zrel + b*RDIM*DDIM + d;
  size_t xb = (size_t)b*VDIM*64 + d;
  float acc0 = 0.f, acc1 = 0.f;
  int i = s;
  for (; i + 2 <= e; i += 2){
    int2 e0 = pk[i], e1 = pk[i+1];
    float x0 = ldf(X, xb + (size_t)e0.y*64);
    float x1 = ldf(X, xb + (size_t)e1.y*64);
    acc0 += zb[(size_t)e0.x*64] * x0;
    acc1 += zb[(size_t)e1.x*64] * x1;
  }
  if (i < e){
    int2 ed = pk[i];
    acc0 += zb[(size_t)ed.x*64] * ldf(X, xb + (size_t)ed.y*64);
  }
  stf(out, ((size_t)b*VDIM + v)*64 + d, acc0 + acc1);
}

// ---- init qk_x: fused MLP, weights pinned in regs (2 waves/EU), prefetch ----
template<typename T>
__global__ __launch_bounds__(256, 2) void init_qk_kernel(
    const float* __restrict__ x, const float* __restrict__ noise,
    const float* __restrict__ w1, const float* __restrict__ b1,
    const float* __restrict__ w2, const float* __restrict__ b2,
    T* __restrict__ out){
  __shared__ __align__(16) float tb[4*64];
  __shared__ __align__(16) float hb[4*64];
  int tid = threadIdx.x, lane = tid & 63, wid = tid >> 6;
  float w1a[64]; float4 w2r[16];
  #pragma unroll
  for (int i = 0; i < 64; i++) w1a[i] = w1[lane*65 + i];
  float wn = w1[lane*65 + 64];
  const float4* w2v = (const float4*)w2;
  #pragma unroll
  for (int i = 0; i < 16; i++) w2r[i] = w2v[lane*16 + i];
  float b1l = b1[lane], b2l = b2[lane];
  const float4* tbv = (const float4*)tb;
  const float4* hbv = (const float4*)hb;
  const size_t end = (size_t)BV*64;
  const size_t stride = (size_t)gridDim.x*256;
  size_t rb = ((size_t)blockIdx.x*4 + wid)*64;
  size_t rowi = (size_t)blockIdx.x*4 + wid;
  float xcur = x[rb+lane];
  float nz = noise[rowi];
  for (; rb < end; rb += stride, rowi += (size_t)gridDim.x*4){
    size_t nrb = rb + stride;
    bool hasn = nrb < end;
    size_t prow = hasn ? nrb : rb;
    float xn = x[prow+lane];
    float nzn = noise[hasn ? rowi + (size_t)gridDim.x*4 : rowi];
    tb[wid*64+lane] = xcur;
    wsync();
    float h = b1l + wn * nz;
    #pragma unroll
    for (int i4 = 0; i4 < 16; i4++){
      float4 t = tbv[wid*16 + i4];
      h += w1a[i4*4+0]*t.x + w1a[i4*4+1]*t.y + w1a[i4*4+2]*t.z + w1a[i4*4+3]*t.w;
    }
    hb[wid*64+lane] = fmaxf(h, 0.f);
    wsync();
    float y = b2l;
    #pragma unroll
    for (int i4 = 0; i4 < 16; i4++) y += dot4(w2r[i4], hbv[wid*16 + i4]);
    stf(out, rb+lane, y);
    wsync();
    xcur = xn; nz = nzn;
  }
}

// ---- init v_x ----
template<typename T>
__global__ __launch_bounds__(256, 2) void init_v_kernel(
    const float* __restrict__ x, const int* __restrict__ h_index,
    const float* __restrict__ w1, const float* __restrict__ b1,
    const float* __restrict__ w2, const float* __restrict__ b2,
    T* __restrict__ out){
  __shared__ __align__(16) float tb[4*64];
  __shared__ __align__(16) float hb[4*64];
  int tid = threadIdx.x, lane = tid & 63, wid = tid >> 6;
  float4 w1r[16], w2r[16];
  const float4* w1v = (const float4*)w1;     // [64][128] -> row stride 32 float4
  const float4* w2v = (const float4*)w2;
  #pragma unroll
  for (int i = 0; i < 16; i++){ w1r[i] = w1v[lane*32 + i]; w2r[i] = w2v[lane*16 + i]; }
  float rsv = 0.f;
  #pragma unroll
  for (int i = 0; i < 16; i++){ float4 t = w1v[lane*32 + 16 + i]; rsv += t.x+t.y+t.z+t.w; }
  float b1l = b1[lane], b2l = b2[lane];
  int h0 = h_index[0], h1 = h_index[1], h2 = h_index[2], h3 = h_index[3];
  const float4* tbv = (const float4*)tb;
  const float4* hbv = (const float4*)hb;
  const size_t end = (size_t)BV*64;
  const size_t stride = (size_t)gridDim.x*256;
  size_t rb = ((size_t)blockIdx.x*4 + wid)*64;
  int rowi = blockIdx.x*4 + wid;
  float xcur = x[rb+lane];
  for (; rb < end; rb += stride, rowi += gridDim.x*4){
    size_t nrb = rb + stride;
    size_t prow = (nrb < end) ? nrb : rb;
    float xn = x[prow+lane];
    int b = rowi / VDIM, v = rowi - b*VDIM;
    int hv = (b == 0) ? h0 : (b == 1) ? h1 : (b == 2) ? h2 : h3;
    tb[wid*64+lane] = xcur;
    wsync();
    float h = b1l + ((v == hv) ? rsv : 0.f);
    #pragma unroll
    for (int i4 = 0; i4 < 16; i4++) h += dot4(w1r[i4], tbv[wid*16 + i4]);
    hb[wid*64+lane] = fmaxf(h, 0.f);
    wsync();
    float y = b2l;
    #pragma unroll
    for (int i4 = 0; i4 < 16; i4++) y += dot4(w2r[i4], hbv[wid*16 + i4]);
    stf(out, rb+lane, y);
    wsync();
    xcur = xn;
  }
}

// ---- loop body: X = LN(mlp2(O + alpha*X))*ng + nb + X ----
template<typename T>
__global__ __launch_bounds__(256, 2) void loop_body_kernel(
    const T* __restrict__ O, T* __restrict__ X,
    const float* __restrict__ alpha, const float* __restrict__ w1, const float* __restrict__ b1,
    const float* __restrict__ w2, const float* __restrict__ b2,
    const float* __restrict__ ng, const float* __restrict__ nb){
  __shared__ __align__(16) float tb[4*64];
  __shared__ __align__(16) float hb[4*64];
  int tid = threadIdx.x, lane = tid & 63, wid = tid >> 6;
  float4 w1r[16], w2r[16];
  const float4* w1v = (const float4*)w1;
  const float4* w2v = (const float4*)w2;
  #pragma unroll
  for (int i = 0; i < 16; i++){ w1r[i] = w1v[lane*16 + i]; w2r[i] = w2v[lane*16 + i]; }
  float all = alpha[lane], b1l = b1[lane], b2l = b2[lane];
  float ngl = ng[lane], nbl = nb[lane];
  const float4* tbv = (const float4*)tb;
  const float4* hbv = (const float4*)hb;
  const size_t end = (size_t)BV*64;
  const size_t stride = (size_t)gridDim.x*256;
  size_t rb = ((size_t)blockIdx.x*4 + wid)*64;
  float xs = ldf(X, rb+lane);
  float ov = ldf(O, rb+lane);
  for (; rb < end; rb += stride){
    size_t nrb = rb + stride;
    size_t prow = (nrb < end) ? nrb : rb;
    float xs_n = ldf(X, prow+lane);
    float ov_n = ldf(O, prow+lane);
    tb[wid*64+lane] = ov + all * xs;
    wsync();
    float h = b1l;
    #pragma unroll
    for (int i4 = 0; i4 < 16; i4++) h += dot4(w1r[i4], tbv[wid*16 + i4]);
    hb[wid*64+lane] = fmaxf(h, 0.f);
    wsync();
    float y = b2l;
    #pragma unroll
    for (int i4 = 0; i4 < 16; i4++) y += dot4(w2r[i4], hbv[wid*16 + i4]);
    float mu = wave_sum64(y) * (1.f/64.f);
    float c = y - mu;
    float var = wave_sum64(c*c) * (1.f/64.f);
    stf(X, rb+lane, c * rsqrtf(var + LN_EPS) * ngl + nbl + xs);
    wsync();
    xs = xs_n; ov = ov_n;
  }
}

// ---- qkproj: weights pinned in regs, no per-iter barriers, prefetched ----
template<typename T>
__global__ __launch_bounds__(256, 2) void qkproj_kernel(
    T* __restrict__ Xqk, const T* __restrict__ Xv,
    const float* __restrict__ w, const float* __restrict__ bias,
    float* __restrict__ partial){
  __shared__ __align__(16) float tb[4*64];
  __shared__ __align__(16) float red[4*1152];
  int tid = threadIdx.x, lane = tid & 63, wid = tid >> 6;
  float4 wq[16], wk[16];
  const float4* wv = (const float4*)w;
  #pragma unroll
  for (int i = 0; i < 16; i++){ wq[i] = wv[lane*16 + i]; wk[i] = wv[(64+lane)*16 + i]; }
  float bq = bias[lane], bk = bias[64+lane];
  int b = blockIdx.x / NBB, blk = blockIdx.x % NBB;
  float kv[16];
  #pragma unroll
  for (int i = 0; i < 16; i++) kv[i] = 0.f;
  float ks = 0.f, vs = 0.f;
  const float4* tbv = (const float4*)tb;
  const int STEPS = VDIM / (NBB*4);          // 20
  int v = blk*4 + wid;
  size_t row = ((size_t)b*VDIM + v)*64;
  const size_t rstride = (size_t)NBB*4*64;
  float xcur = ldf(Xqk, row+lane);
  float vcur = ldf(Xv, row+lane);
  int base = lane & 48;                      // h*16
  for (int st = 0; st < STEPS; st++){
    size_t nrow = row + rstride;
    size_t prow = (st + 1 < STEPS) ? nrow : row;
    float xn = ldf(Xqk, prow+lane);
    float vn = ldf(Xv, prow+lane);
    tb[wid*64+lane] = xcur;
    wsync();
    float q = bq, k = bk;
    #pragma unroll
    for (int i4 = 0; i4 < 16; i4++){
      float4 t = tbv[wid*16 + i4];
      q += dot4(wq[i4], t);
      k += dot4(wk[i4], t);
    }
    wsync();
    float qn2 = head_sum16(q*q);
    float kn2 = head_sum16(k*k);
    q = q / fmaxf(sqrtf(qn2), 1e-12f);
    k = k / fmaxf(sqrtf(kn2), 1e-12f);
    stf(Xqk, row+lane, q);                   // qn in place
    ks += k; vs += vcur;
    #pragma unroll
    for (int dl = 0; dl < 16; dl++){
      float vdl = __shfl(vcur, base + dl, 64);
      kv[dl] += k * vdl;
    }
    row = nrow; xcur = xn; vcur = vn;
  }
  // per-wave partials -> LDS -> block partial (coalesced)
  float* rw = red + wid*1152;
  #pragma unroll
  for (int dl = 0; dl < 16; dl++) rw[lane*16 + dl] = kv[dl];
  rw[1024 + lane] = ks;
  rw[1088 + lane] = vs;
  __syncthreads();
  float* P = partial + (size_t)blockIdx.x*1152;
  for (int j = tid; j < 1152; j += 256)
    P[j] = red[j] + red[1152+j] + red[2304+j] + red[3456+j];
}

// ---- reduce qkproj partials ----
__global__ void qkred_kernel(const float* __restrict__ partial,
                             float* __restrict__ kvs, float* __restrict__ ksum, float* __restrict__ vsum){
  int b = blockIdx.x / 5, ch = blockIdx.x % 5;
  int j = ch*256 + threadIdx.x;
  if (j >= 1152) return;
  const float* P = partial + (size_t)b*NBB*1152;
  float s = 0.f;
  for (int t = 0; t < NBB; t++) s += P[(size_t)t*1152 + j];
  if (j < 1024)      kvs[b*1024 + j] = s;
  else if (j < 1088) ksum[b*64 + (j-1024)] = s;
  else               vsum[b*64 + (j-1088)] = s;
}

// ---- attention finalize + LN (prefetched streams) ----
template<typename T>
__global__ __launch_bounds__(256) void attn_final_kernel(
    const float* __restrict__ x, T* __restrict__ A, const T* __restrict__ Xv,
    const float* __restrict__ kvs, const float* __restrict__ ksum, const float* __restrict__ vsum,
    const float* __restrict__ g, const float* __restrict__ bb){
  __shared__ float kvss[4096], kss[256], vss[256];
  int tid = threadIdx.x, lane = tid & 63, wid = tid >> 6;
  for (int i = tid; i < 4096; i += 256) kvss[i] = kvs[i];
  kss[tid] = ksum[tid];
  vss[tid] = vsum[tid];
  float gl = g[lane], bl = bb[lane];
  __syncthreads();
  int h16 = lane & 48, dl = lane & 15;
  const size_t end = (size_t)BV*64;
  const size_t stride = (size_t)gridDim.x*256;
  size_t rb = ((size_t)blockIdx.x*4 + wid)*64;
  int rowi = blockIdx.x*4 + wid;
  float qv = ldf(A, rb+lane);
  float vv = ldf(Xv, rb+lane);
  float xv = x[rb+lane];
  for (; rb < end; rb += stride, rowi += gridDim.x*4){
    size_t nrb = rb + stride;
    size_t prow = (nrb < end) ? nrb : rb;
    float qn_ = ldf(A, prow+lane);
    float vn_ = ldf(Xv, prow+lane);
    float xn_ = x[prow+lane];
    int b = rowi / VDIM;
    float num = vss[b*64+lane] + vv * (float)VDIM;
    float den = 2.0f * (float)VDIM;
    int kbase = b*1024 + h16*16 + dl;
    int ksbase = b*64 + h16;
    #pragma unroll
    for (int j = 0; j < 16; j++){
      float qj = __shfl(qv, h16 + j, 64);
      num += qj * kvss[kbase + j*16];
      den += qj * kss[ksbase + j];
    }
    float y = xv + num / den;
    float mu = wave_sum64(y) * (1.f/64.f);
    float c = y - mu;
    float var = wave_sum64(c*c) * (1.f/64.f);
    stf(A, rb+lane, c * rsqrtf(var + LN_EPS) * gl + bl);
    qv = qn_; vv = vn_; xv = xn_;
  }
}

// ---- final FFN + LN -> fp32 out ----
template<typename T>
__global__ __launch_bounds__(256, 2) void final_kernel(
    const T* __restrict__ X1,
    const float* __restrict__ w1, const float* __restrict__ b1,
    const float* __restrict__ w2, const float* __restrict__ b2,
    const float* __restrict__ g, const float* __restrict__ bb,
    float* __restrict__ out){
  __shared__ __align__(16) float tb[4*64];
  __shared__ __align__(16) float hb[4*64];
  int tid = threadIdx.x, lane = tid & 63, wid = tid >> 6;
  float4 w1r[16], w2r[16];
  const float4* w1v = (const float4*)w1;
  const float4* w2v = (const float4*)w2;
  #pragma unroll
  for (int i = 0; i < 16; i++){ w1r[i] = w1v[lane*16 + i]; w2r[i] = w2v[lane*16 + i]; }
  float b1l = b1[lane], b2l = b2[lane], gl = g[lane], bl = bb[lane];
  const float4* tbv = (const float4*)tb;
  const float4* hbv = (const float4*)hb;
  const size_t end = (size_t)BV*64;
  const size_t stride = (size_t)gridDim.x*256;
  size_t rb = ((size_t)blockIdx.x*4 + wid)*64;
  float xcur = ldf(X1, rb+lane);
  for (; rb < end; rb += stride){
    size_t nrb = rb + stride;
    size_t prow = (nrb < end) ? nrb : rb;
    float xn = ldf(X1, prow+lane);
    tb[wid*64+lane] = xcur;
    wsync();
    float h = b1l;
    #pragma unroll
    for (int i4 = 0; i4 < 16; i4++) h += dot4(w1r[i4], tbv[wid*16 + i4]);
    hb[wid*64+lane] = fmaxf(h, 0.f);
    wsync();
    float y = b2l;
    #pragma unroll
    for (int i4 = 0; i4 < 16; i4++) y += dot4(w2r[i4], hbv[wid*16 + i4]);
    float t = xcur + y;
    float mu = wave_sum64(t) * (1.f/64.f);
    float c = t - mu;
    float var = wave_sum64(c*c) * (1.f/64.f);
    out[rb+lane] = c * rsqrtf(var + LN_EPS) * gl + bl;
    wsync();
    xcur = xn;
  }
}

// ================= host side =================
static const int DICT_SIZES[42] = {
  5120000,256,256,80000,262144,4096,4160,64,4096,64,
  8192,64,4096,64,8192,128,8192,128,8192,128,
  128,128,128,524288,8192,8192,128,8192,128,128,
  128,128,4096,64,4096,64,64,64,64,64,
  4,600000};

template<typename T>
static void run_pipeline(const float* const* N, const int* hi,
                         const int* row_ptr, const int2* pk,
                         float* qk_z, float* zr, float* kvs, float* part,
                         T* Obuf, T* A, T* B, float* outp, hipStream_t stream){
  float* ksum = kvs + 4096;
  float* vsum = kvs + 4352;
  const int GM = 2000;

  zcalc_kernel<<<192, 256, 0, stream>>>(N[1], N[4], N[5], N[23], N[24], qk_z, zr);

  init_qk_kernel<T><<<GM, 256, 0, stream>>>(N[0], N[3], N[6], N[7], N[8], N[9], A);
  for (int i = 0; i < 2; i++){
    rspmm_gather<T><<<VDIM, 256, 0, stream>>>(row_ptr, pk, qk_z, A, Obuf);
    loop_body_kernel<T><<<GM, 256, 0, stream>>>(Obuf, A, N[20] + i*64, N[16] + i*4096, N[17] + i*64,
                                                N[18] + i*4096, N[19] + i*64, N[21] + i*64, N[22] + i*64);
  }
  init_v_kernel<T><<<GM, 256, 0, stream>>>(N[0], hi, N[10], N[11], N[12], N[13], B);
  for (int i = 0; i < 2; i++){
    rspmm_gather<T><<<VDIM, 256, 0, stream>>>(row_ptr, pk, zr + i*16384, B, Obuf);
    loop_body_kernel<T><<<GM, 256, 0, stream>>>(Obuf, B, N[29] + i*64, N[25] + i*4096, N[26] + i*64,
                                                N[27] + i*4096, N[28] + i*64, N[30] + i*64, N[31] + i*64);
  }
  qkproj_kernel<T><<<BDIM*NBB, 256, 0, stream>>>(A, B, N[14], N[15], part);
  qkred_kernel<<<20, 256, 0, stream>>>(part, kvs, ksum, vsum);
  attn_final_kernel<T><<<GM, 256, 0, stream>>>(N[0], A, B, kvs, ksum, vsum, N[36], N[37]);
  final_kernel<T><<<GM, 256, 0, stream>>>(A, N[32], N[33], N[34], N[35], N[38], N[39], outp);
}

extern "C" void kernel_launch(void* const* d_in, const int* in_sizes, int n_in,
                              void* d_out, int out_size, void* d_ws, size_t ws_size,
                              hipStream_t stream){
  float* outp = (float*)d_out;
  const int GOUT = (out_size + 255) / 256;

  if (n_in != 42){
    fill_kernel<<<GOUT, 256, 0, stream>>>(outp, 2000.0f + (float)n_in, out_size);
    return;
  }
  auto sz_ok = [&](int s, int e)->bool{
    if (s == e) return true;
    if ((e == 4 || e == 600000) && s == 2*e) return true;
    return false;
  };
  int bad = -1;
  for (int i = 0; i < 42 && bad < 0; i++)
    if (!sz_ok(in_sizes[i], DICT_SIZES[i])) bad = i;
  if (bad >= 0){
    fill_kernel<<<GOUT, 256, 0, stream>>>(outp, 1000.0f + (float)bad, out_size);
    return;
  }

  const float* N[40];
  for (int i = 0; i < 40; i++) N[i] = (const float*)d_in[i];
  const int* hi_raw = (const int*)d_in[40];
  const int* ei_raw = (const int*)d_in[41];

  char* p = (char*)d_ws;
  auto alloc = [&](size_t bytes)->char*{ char* r = p; p += (bytes + 255) / 256 * 256; return r; };
  int* ei      = (int*)alloc((size_t)3*EDIM*4);
  int* hi      = (int*)alloc(256);
  int* eflag   = (int*)alloc(256);
  int* counts  = (int*)alloc((VDIM+1)*4);
  int* row_ptr = (int*)alloc((VDIM+1)*4);
  int* cursor  = (int*)alloc((VDIM+1)*4);
  int2* pk     = (int2*)alloc((size_t)EDIM*8);
  float* qk_z  = (float*)alloc(16384u*4);
  float* zr    = (float*)alloc(32768u*4);
  float* kvs   = (float*)alloc(4608u*4);
  float* part  = (float*)alloc((size_t)BDIM*NBB*1152*4);
  size_t fixed = (size_t)(p - (char*)d_ws);
  bool f32ok = ws_size >= fixed + 3*(size_t)BV*64*4 + 1024;

  detect_kernel<<<1, 256, 0, stream>>>(ei_raw, eflag);
  prep_idx_kernel<<<(3*EDIM+255)/256, 256, 0, stream>>>(ei_raw, hi_raw, eflag, ei, hi);
  zero_kernel<<<(VDIM+256)/256, 256, 0, stream>>>(counts);
  count_kernel<<<(EDIM+255)/256, 256, 0, stream>>>(ei, counts);
  scan_kernel<<<1, 256, 0, stream>>>(counts, row_ptr, cursor);
  scatter_kernel<<<(EDIM+255)/256, 256, 0, stream>>>(ei, cursor, pk);

  if (f32ok){
    float* Obuf = (float*)alloc((size_t)BV*64*4);
    float* A    = (float*)alloc((size_t)BV*64*4);
    float* B    = (float*)alloc((size_t)BV*64*4);
    run_pipeline<float>(N, hi, row_ptr, pk, qk_z, zr, kvs, part, Obuf, A, B, outp, stream);
  } else {
    bf16* Obuf = (bf16*)alloc((size_t)BV*64*2);
    bf16* A    = (bf16*)alloc((size_t)BV*64*2);
    bf16* B    = (bf16*)alloc((size_t)BV*64*2);
    run_pipeline<bf16>(N, hi, row_ptr, pk, qk_z, zr, kvs, part, Obuf, A, B, outp, stream);
  }
}